// Round 8
// baseline (349.865 us; speedup 1.0000x reference)
//
#include <hip/hip_runtime.h>
#include <hip/hip_fp16.h>

// GCN 3-layer: N=50000, E=800000, dims 128->128->128->64, fp32 in/out.
// Norm factorization: norm[e]=dinv[s]*dinv[d] is separable, so GEMM epilogue
// emits xwh = dinv[row]*xw in fp16; agg sums xwh rows (plain adds), scales by
// dinv[dst] once, adds fp32 self-loop + bias. CSR = src only (4B/edge).
// GEMM: W-only LDS (32KB) -> 4 blocks/CU; X read direct from global (L1/bcast).

#define C_IN 128
#define C_HID 128
#define C_OUT 64
#define SCAN_T 256
#define SCAN_ELEMS (SCAN_T * 4)

// ---------------- CSR build ----------------

__global__ void count_deg_kernel(const int* __restrict__ dst, int E, int* __restrict__ degi) {
    int e = blockIdx.x * blockDim.x + threadIdx.x;
    if (e < E) atomicAdd(&degi[dst[e]], 1);
}

// pass 1: per-block (1024 elems) exclusive scan + block totals; also emits dinv.
__global__ void scan1_kernel(const int* __restrict__ degi, int n,
                             int* __restrict__ excl, int* __restrict__ partials,
                             float* __restrict__ dinv) {
    __shared__ int lds[SCAN_T];
    int tid = threadIdx.x;
    int base = blockIdx.x * SCAN_ELEMS + tid * 4;
    int a0 = (base + 0 < n) ? degi[base + 0] : 0;
    int a1 = (base + 1 < n) ? degi[base + 1] : 0;
    int a2 = (base + 2 < n) ? degi[base + 2] : 0;
    int a3 = (base + 3 < n) ? degi[base + 3] : 0;
    if (base + 0 < n) dinv[base + 0] = rsqrtf((float)a0 + 1.0f);
    if (base + 1 < n) dinv[base + 1] = rsqrtf((float)a1 + 1.0f);
    if (base + 2 < n) dinv[base + 2] = rsqrtf((float)a2 + 1.0f);
    if (base + 3 < n) dinv[base + 3] = rsqrtf((float)a3 + 1.0f);
    int t = a0 + a1 + a2 + a3;
    lds[tid] = t;
    __syncthreads();
    for (int off = 1; off < SCAN_T; off <<= 1) {
        int v = (tid >= off) ? lds[tid - off] : 0;
        __syncthreads();
        lds[tid] += v;
        __syncthreads();
    }
    int incl = lds[tid];
    int ex = incl - t;
    if (base + 0 < n) excl[base + 0] = ex;
    if (base + 1 < n) excl[base + 1] = ex + a0;
    if (base + 2 < n) excl[base + 2] = ex + a0 + a1;
    if (base + 3 < n) excl[base + 3] = ex + a0 + a1 + a2;
    if (tid == SCAN_T - 1) partials[blockIdx.x] = incl;
}

__global__ void scan2_kernel(int* __restrict__ partials, int nb) {
    if (threadIdx.x == 0 && blockIdx.x == 0) {
        int run = 0;
        for (int i = 0; i < nb; ++i) { int v = partials[i]; partials[i] = run; run += v; }
    }
}

__global__ void scan3_kernel(int* __restrict__ excl, const int* __restrict__ partials, int n) {
    int gid = blockIdx.x * blockDim.x + threadIdx.x;
    if (gid < n) excl[gid] += partials[gid / SCAN_ELEMS];
}

// fill: atomicAdd directly on rowptr (destructive). After this kernel,
// rowptr[i] == start of row i+1.  csr entry = src only (norm is factored out).
__global__ void fill_csr_kernel(const int* __restrict__ src, const int* __restrict__ dst, int E,
                                int* __restrict__ rowptr, int* __restrict__ csr) {
    int e = blockIdx.x * blockDim.x + threadIdx.x;
    if (e >= E) return;
    int s = src[e], d = dst[e];
    int pos = atomicAdd(&rowptr[d], 1);
    csr[pos] = s;
}

// ------- GEMM: X[n,128] @ W[128,FOUT] -> Y (fp32), Yh = dinv[row]*Y (fp16) -------
// W slice staged in LDS (32KB); X read straight from global (rows walk 64B
// lines sequentially; 16 same-row lanes broadcast). 4 blocks/CU.
template <int FOUT>
__global__ __launch_bounds__(256, 4) void gemm_k128(const float* __restrict__ X,
                                                    const float* __restrict__ W,
                                                    const float* __restrict__ dinv,
                                                    float* __restrict__ Y,
                                                    __half* __restrict__ Yh, int n) {
    constexpr int K = 128;
    constexpr int CT = 64;
    constexpr int MT = 64;
    constexpr int NQ = CT / 4;
    constexpr int RPT = 4;
    __shared__ float Ws[K][CT];   // 32 KB

    int tid = threadIdx.x;
    int row0 = blockIdx.x * MT;
    int col0 = blockIdx.y * CT;

#pragma unroll
    for (int i = 0; i < (K * CT / 4) / 256; ++i) {
        int idx = tid + i * 256;
        int k = idx / (CT / 4);
        int c = idx % (CT / 4);
        *(float4*)&Ws[k][c * 4] = *(const float4*)(W + (size_t)k * FOUT + col0 + c * 4);
    }
    __syncthreads();

    int cq = tid % NQ;
    int rg = tid / NQ;
    int r0 = row0 + rg * RPT;

    const float* xb[RPT];
#pragma unroll
    for (int r = 0; r < RPT; ++r) {
        int gr = r0 + r;
        if (gr > n - 1) gr = n - 1;       // clamp (stores are guarded)
        xb[r] = X + (size_t)gr * K;
    }

    float acc[RPT][4] = {};
#pragma unroll 4
    for (int k4 = 0; k4 < K / 4; ++k4) {
        float4 xa[RPT];
#pragma unroll
        for (int r = 0; r < RPT; ++r)
            xa[r] = *(const float4*)(xb[r] + k4 * 4);
#pragma unroll
        for (int kk = 0; kk < 4; ++kk) {
            float4 w = *(float4*)&Ws[k4 * 4 + kk][cq * 4];
#pragma unroll
            for (int r = 0; r < RPT; ++r) {
                float xarr[4] = {xa[r].x, xa[r].y, xa[r].z, xa[r].w};
                float xv = xarr[kk];
                acc[r][0] = fmaf(xv, w.x, acc[r][0]);
                acc[r][1] = fmaf(xv, w.y, acc[r][1]);
                acc[r][2] = fmaf(xv, w.z, acc[r][2]);
                acc[r][3] = fmaf(xv, w.w, acc[r][3]);
            }
        }
    }
#pragma unroll
    for (int r = 0; r < RPT; ++r) {
        int gr = r0 + r;
        if (gr < n) {
            size_t off = (size_t)gr * FOUT + col0 + cq * 4;
            *(float4*)(Y + off) =
                make_float4(acc[r][0], acc[r][1], acc[r][2], acc[r][3]);
            float di = dinv[gr];
            __half2 h01 = __floats2half2_rn(acc[r][0] * di, acc[r][1] * di);
            __half2 h23 = __floats2half2_rn(acc[r][2] * di, acc[r][3] * di);
            uint2 pk = make_uint2(*(unsigned int*)&h01, *(unsigned int*)&h23);
            *(uint2*)(Yh + off) = pk;
        }
    }
}

// ---------------- aggregate helpers ----------------
// One batch of NB edges: NB wave-uniform csr reads (4B src) -> NB independent
// fp16 row gathers (pre-scaled by dinv[src]) -> fp32 adds into acc[0..3].
// MASK: clamp edge index into the row; zero the value for k >= rem.

template <int NB, bool MASK>
__device__ __forceinline__ void batch_f128(const int* __restrict__ csr, int j, int rem,
                                           const __half* __restrict__ xwh, int lane,
                                           float2* acc) {
    int s[NB];
#pragma unroll
    for (int k = 0; k < NB; ++k) {
        int jj = MASK ? (j + ((k < rem) ? k : 0)) : (j + k);
        s[k] = csr[jj];
    }
    float2 v[NB];
#pragma unroll
    for (int k = 0; k < NB; ++k) {
        __half2 hv = ((const __half2*)(xwh + (size_t)s[k] * 128))[lane];
        v[k] = __half22float2(hv);
    }
#pragma unroll
    for (int k = 0; k < NB; ++k) {
        float m = (!MASK || (k < rem)) ? 1.0f : 0.0f;
        acc[k & 3].x = fmaf(v[k].x, m, acc[k & 3].x);
        acc[k & 3].y = fmaf(v[k].y, m, acc[k & 3].y);
    }
}

template <int NB, bool MASK>
__device__ __forceinline__ void batch_f64(const int* __restrict__ csr, int j, int rem,
                                          const __half* __restrict__ xwh, int lane,
                                          float* acc) {
    int s[NB];
#pragma unroll
    for (int k = 0; k < NB; ++k) {
        int jj = MASK ? (j + ((k < rem) ? k : 0)) : (j + k);
        s[k] = csr[jj];
    }
    float v[NB];
#pragma unroll
    for (int k = 0; k < NB; ++k)
        v[k] = __half2float(xwh[(size_t)s[k] * 64 + lane]);
#pragma unroll
    for (int k = 0; k < NB; ++k) {
        float m = (!MASK || (k < rem)) ? 1.0f : 0.0f;
        acc[k & 3] = fmaf(v[k], m, acc[k & 3]);
    }
}

// --- fused aggregate: out = dinv[i]*sum_j xwh[src_j] + xw[i]*dinv^2 + b [+relu] ---
// rowptr is the post-fill shifted array: row i spans [i==0?0:rowptr[i-1], rowptr[i]).
template <int F, bool RELU>
__global__ __launch_bounds__(256) void agg_kernel(const int* __restrict__ rowptr,
                                                  const int* __restrict__ csr,
                                                  const float* __restrict__ xw,
                                                  const __half* __restrict__ xwh,
                                                  const float* __restrict__ dinv,
                                                  const float* __restrict__ bias,
                                                  float* __restrict__ out, int n) {
    int wave = threadIdx.x >> 6;
    int lane = threadIdx.x & 63;
    int i0 = blockIdx.x * 4 + wave;
    if (i0 >= n) return;
    // node index is wave-uniform: pin to SGPR so rowptr/csr reads go scalar.
    int i = __builtin_amdgcn_readfirstlane(i0);
    float di = dinv[i];
    float d2 = di * di;
    int j = (i == 0) ? 0 : rowptr[i - 1];
    int end = rowptr[i];
    j = __builtin_amdgcn_readfirstlane(j);
    end = __builtin_amdgcn_readfirstlane(end);

    if constexpr (F == 128) {
        float2 x0 = ((const float2*)(xw + (size_t)i * F))[lane];   // fp32 self-loop
        float2 acc[4];
        acc[0] = acc[1] = acc[2] = acc[3] = make_float2(0.f, 0.f);

        for (; j + 16 <= end; j += 16) batch_f128<16, false>(csr, j, 0, xwh, lane, acc);
        if (j + 8 <= end) { batch_f128<8, false>(csr, j, 0, xwh, lane, acc); j += 8; }
        if (j + 4 <= end) { batch_f128<4, false>(csr, j, 0, xwh, lane, acc); j += 4; }
        int rem = end - j;
        if (rem > 0) batch_f128<4, true>(csr, j, rem, xwh, lane, acc);

        float2 bv = ((const float2*)bias)[lane];
        float2 o;
        o.x = fmaf(di, (acc[0].x + acc[1].x) + (acc[2].x + acc[3].x),
                   fmaf(x0.x, d2, bv.x));
        o.y = fmaf(di, (acc[0].y + acc[1].y) + (acc[2].y + acc[3].y),
                   fmaf(x0.y, d2, bv.y));
        if (RELU) { o.x = fmaxf(o.x, 0.f); o.y = fmaxf(o.y, 0.f); }
        ((float2*)(out + (size_t)i * F))[lane] = o;
    } else {  // F == 64
        float x0 = xw[(size_t)i * F + lane];                        // fp32 self-loop
        float acc[4] = {0.f, 0.f, 0.f, 0.f};

        for (; j + 16 <= end; j += 16) batch_f64<16, false>(csr, j, 0, xwh, lane, acc);
        if (j + 8 <= end) { batch_f64<8, false>(csr, j, 0, xwh, lane, acc); j += 8; }
        if (j + 4 <= end) { batch_f64<4, false>(csr, j, 0, xwh, lane, acc); j += 4; }
        int rem = end - j;
        if (rem > 0) batch_f64<4, true>(csr, j, rem, xwh, lane, acc);

        float o = fmaf(di, (acc[0] + acc[1]) + (acc[2] + acc[3]),
                       fmaf(x0, d2, bias[lane]));
        if (RELU) o = fmaxf(o, 0.f);
        out[(size_t)i * F + lane] = o;
    }
}

extern "C" void kernel_launch(void* const* d_in, const int* in_sizes, int n_in,
                              void* d_out, int out_size, void* d_ws, size_t ws_size,
                              hipStream_t stream) {
    const float* x  = (const float*)d_in[0];
    const int*   ei = (const int*)d_in[1];
    const float* W1 = (const float*)d_in[2];
    const float* b1 = (const float*)d_in[3];
    const float* W2 = (const float*)d_in[4];
    const float* b2 = (const float*)d_in[5];
    const float* W3 = (const float*)d_in[6];
    const float* b3 = (const float*)d_in[7];
    float* out = (float*)d_out;

    int E = in_sizes[1] / 2;
    int n = in_sizes[0] / C_IN;
    const int* src = ei;
    const int* dst = ei + E;

    // workspace layout
    float*  A        = (float*)d_ws;                     // [n*128] xw fp32
    float*  B        = A + (size_t)n * C_HID;            // [n*128] h fp32
    __half* Ah       = (__half*)(B + (size_t)n * C_HID); // [n*128] dinv*xw fp16
    int*    csr      = (int*)(Ah + (size_t)n * C_HID);   // [E] src only
    float*  dinv     = (float*)(csr + E);                // [n]
    int*    degi     = (int*)(dinv + n);                 // [n]
    int*    rowptr   = degi + n;                         // [n+1]
    int*    partials = rowptr + n + 1;                   // [<=64]

    int nb = (n + SCAN_ELEMS - 1) / SCAN_ELEMS;

    // ---- CSR build (once; reused by all 3 layers) ----
    hipMemsetAsync(degi, 0, (size_t)n * sizeof(int), stream);
    count_deg_kernel<<<(E + 255) / 256, 256, 0, stream>>>(dst, E, degi);
    scan1_kernel<<<nb, SCAN_T, 0, stream>>>(degi, n, rowptr, partials, dinv);
    scan2_kernel<<<1, 64, 0, stream>>>(partials, nb);
    scan3_kernel<<<(n + 255) / 256, 256, 0, stream>>>(rowptr, partials, n);
    fill_csr_kernel<<<(E + 255) / 256, 256, 0, stream>>>(src, dst, E, rowptr, csr);

    dim3 g128((n + 63) / 64, C_HID / 64);
    dim3 g64((n + 63) / 64, 1);
    int aggBlocks = (n + 3) / 4;

    // ---- layer 1 ----
    gemm_k128<C_HID><<<g128, 256, 0, stream>>>(x, W1, dinv, A, Ah, n);
    agg_kernel<C_HID, false><<<aggBlocks, 256, 0, stream>>>(rowptr, csr, A, Ah, dinv, b1, B, n);
    // ---- layer 2 ----
    gemm_k128<C_HID><<<g128, 256, 0, stream>>>(B, W2, dinv, A, Ah, n);
    agg_kernel<C_HID, false><<<aggBlocks, 256, 0, stream>>>(rowptr, csr, A, Ah, dinv, b2, B, n);
    // ---- layer 3 ----
    gemm_k128<C_OUT><<<g64, 256, 0, stream>>>(B, W3, dinv, A, Ah, n);
    agg_kernel<C_OUT, true><<<aggBlocks, 256, 0, stream>>>(rowptr, csr, A, Ah, dinv, b3, out, n);
}

// Round 9
// 306.576 us; speedup vs baseline: 1.1412x; 1.1412x over previous
//
#include <hip/hip_runtime.h>
#include <hip/hip_fp16.h>

// GCN 3-layer: N=50000, E=800000, dims 128->128->128->64, fp32 in/out.
// Norm factorization: GEMM epilogue emits xwh = dinv[row]*xw (fp16); agg sums
// xwh rows, scales by dinv[dst], adds fp32 self-loop + bias. CSR = src (4B).
// R8: CSR built by bucketed two-level counting sort. Random scatters are
// confined to block-local L2-resident regions (R7 lesson: random 4B global
// writes cost a full 64B HBM line each -> 52.8MB for 3.2MB of payload).

#define C_IN 128
#define C_HID 128
#define C_OUT 64
#define PART_BLOCKS 256   // blocks in hist/place kernels

// ---------------- CSR build: bucketed counting sort ----------------
// bucket b = dst >> 8 (256 nodes per bucket, nbuk = ceil(n/256) = 196)

// A1: global bucket histogram (LDS-privatized)
__global__ __launch_bounds__(256) void buk_hist_kernel(const int* __restrict__ dst, int E,
                                                       int* __restrict__ bukCnt) {
    __shared__ int h[256];
    int tid = threadIdx.x;
    h[tid] = 0;
    __syncthreads();
    int chunk = (E + gridDim.x - 1) / gridDim.x;
    int lo = blockIdx.x * chunk;
    int hi = min(lo + chunk, E);
    for (int e = lo + tid; e < hi; e += 256)
        atomicAdd(&h[dst[e] >> 8], 1);
    __syncthreads();
    if (h[tid] > 0) atomicAdd(&bukCnt[tid], h[tid]);
}

// A2: scan 196 bucket counts -> bases (bbase[nbuk]=E) and working cursors
__global__ __launch_bounds__(256) void buk_scan_kernel(const int* __restrict__ bukCnt,
                                                       int nbuk, int E,
                                                       int* __restrict__ bbase,
                                                       int* __restrict__ cursor) {
    __shared__ int lds[256];
    int tid = threadIdx.x;
    int v = (tid < nbuk) ? bukCnt[tid] : 0;
    lds[tid] = v;
    __syncthreads();
    for (int off = 1; off < 256; off <<= 1) {
        int u = (tid >= off) ? lds[tid - off] : 0;
        __syncthreads();
        lds[tid] += u;
        __syncthreads();
    }
    int ex = lds[tid] - v;
    if (tid < nbuk) { bbase[tid] = ex; cursor[tid] = ex; }
    if (tid == 0) bbase[nbuk] = E;
}

// A3: partition edges into bucket regions. Each block: local hist over its
// chunk, ONE atomicAdd per bucket to reserve a contiguous range (~16 edges =
// 128B), then place -> writes are near-sequential chunks, not line-thrash.
__global__ __launch_bounds__(256) void buk_place_kernel(const int* __restrict__ src,
                                                        const int* __restrict__ dst, int E,
                                                        int* __restrict__ cursor,
                                                        int2* __restrict__ ebuf) {
    __shared__ int h[256];
    __shared__ int base[256];
    __shared__ int c2[256];
    int tid = threadIdx.x;
    h[tid] = 0;
    c2[tid] = 0;
    __syncthreads();
    int chunk = (E + gridDim.x - 1) / gridDim.x;
    int lo = blockIdx.x * chunk;
    int hi = min(lo + chunk, E);
    for (int e = lo + tid; e < hi; e += 256)
        atomicAdd(&h[dst[e] >> 8], 1);
    __syncthreads();
    int cnt = h[tid];
    if (cnt > 0) base[tid] = atomicAdd(&cursor[tid], cnt);
    __syncthreads();
    for (int e = lo + tid; e < hi; e += 256) {
        int d = dst[e];
        int b = d >> 8;
        int slot = base[b] + atomicAdd(&c2[b], 1);
        ebuf[slot] = make_int2(src[e], d);
    }
}

// B: one block per bucket. Sequential read of bucket edges; LDS per-node
// histogram + scan -> rowptr (clean, global slots) + dinv; place csr (src
// only) with scatter confined to the bucket's ~16KB L2-local region.
__global__ __launch_bounds__(256) void buk_fill_kernel(const int2* __restrict__ ebuf,
                                                       const int* __restrict__ bbase,
                                                       int n, int E,
                                                       int* __restrict__ rowptr,
                                                       float* __restrict__ dinv,
                                                       int* __restrict__ csr) {
    __shared__ int deg[256];
    __shared__ int lds[256];
    int b = blockIdx.x;
    int tid = threadIdx.x;
    int lo = bbase[b];
    int hi = bbase[b + 1];
    int node0 = b << 8;
    deg[tid] = 0;
    __syncthreads();
    for (int e = lo + tid; e < hi; e += 256)
        atomicAdd(&deg[ebuf[e].y & 255], 1);
    __syncthreads();
    int d = deg[tid];
    lds[tid] = d;
    __syncthreads();
    for (int off = 1; off < 256; off <<= 1) {
        int u = (tid >= off) ? lds[tid - off] : 0;
        __syncthreads();
        lds[tid] += u;
        __syncthreads();
    }
    int ex = lds[tid] - d;
    int node = node0 + tid;
    if (node < n) {
        rowptr[node] = lo + ex;
        dinv[node] = rsqrtf((float)d + 1.0f);
    }
    if (tid == 0)
        rowptr[min(node0 + 256, n)] = hi;   // next bucket's base / E sentinel
    __syncthreads();
    deg[tid] = lo + ex;                      // running global-slot cursor
    __syncthreads();
    for (int e = lo + tid; e < hi; e += 256) {
        int2 ed = ebuf[e];
        int slot = atomicAdd(&deg[ed.y & 255], 1);
        csr[slot] = ed.x;
    }
}

// ------- GEMM: X[n,128] @ W[128,FOUT] -> Y (fp32), Yh = dinv[row]*Y (fp16) -------
template <int FOUT>
__global__ __launch_bounds__(256, 4) void gemm_k128(const float* __restrict__ X,
                                                    const float* __restrict__ W,
                                                    const float* __restrict__ dinv,
                                                    float* __restrict__ Y,
                                                    __half* __restrict__ Yh, int n) {
    constexpr int K = 128;
    constexpr int CT = 64;
    constexpr int MT = 64;
    constexpr int NQ = CT / 4;
    constexpr int RPT = 4;
    __shared__ float Ws[K][CT];   // 32 KB

    int tid = threadIdx.x;
    int row0 = blockIdx.x * MT;
    int col0 = blockIdx.y * CT;

#pragma unroll
    for (int i = 0; i < (K * CT / 4) / 256; ++i) {
        int idx = tid + i * 256;
        int k = idx / (CT / 4);
        int c = idx % (CT / 4);
        *(float4*)&Ws[k][c * 4] = *(const float4*)(W + (size_t)k * FOUT + col0 + c * 4);
    }
    __syncthreads();

    int cq = tid % NQ;
    int rg = tid / NQ;
    int r0 = row0 + rg * RPT;

    const float* xb[RPT];
#pragma unroll
    for (int r = 0; r < RPT; ++r) {
        int gr = r0 + r;
        if (gr > n - 1) gr = n - 1;       // clamp (stores are guarded)
        xb[r] = X + (size_t)gr * K;
    }

    float acc[RPT][4] = {};
#pragma unroll 4
    for (int k4 = 0; k4 < K / 4; ++k4) {
        float4 xa[RPT];
#pragma unroll
        for (int r = 0; r < RPT; ++r)
            xa[r] = *(const float4*)(xb[r] + k4 * 4);
#pragma unroll
        for (int kk = 0; kk < 4; ++kk) {
            float4 w = *(float4*)&Ws[k4 * 4 + kk][cq * 4];
#pragma unroll
            for (int r = 0; r < RPT; ++r) {
                float xarr[4] = {xa[r].x, xa[r].y, xa[r].z, xa[r].w};
                float xv = xarr[kk];
                acc[r][0] = fmaf(xv, w.x, acc[r][0]);
                acc[r][1] = fmaf(xv, w.y, acc[r][1]);
                acc[r][2] = fmaf(xv, w.z, acc[r][2]);
                acc[r][3] = fmaf(xv, w.w, acc[r][3]);
            }
        }
    }
#pragma unroll
    for (int r = 0; r < RPT; ++r) {
        int gr = r0 + r;
        if (gr < n) {
            size_t off = (size_t)gr * FOUT + col0 + cq * 4;
            *(float4*)(Y + off) =
                make_float4(acc[r][0], acc[r][1], acc[r][2], acc[r][3]);
            float di = dinv[gr];
            __half2 h01 = __floats2half2_rn(acc[r][0] * di, acc[r][1] * di);
            __half2 h23 = __floats2half2_rn(acc[r][2] * di, acc[r][3] * di);
            uint2 pk = make_uint2(*(unsigned int*)&h01, *(unsigned int*)&h23);
            *(uint2*)(Yh + off) = pk;
        }
    }
}

// ---------------- aggregate helpers ----------------
// One batch of NB edges: NB wave-uniform csr reads (4B src) -> NB independent
// fp16 row gathers (pre-scaled by dinv[src]) -> fp32 adds into acc[0..3].
// MASK: clamp edge index into the row; zero the value for k >= rem.

template <int NB, bool MASK>
__device__ __forceinline__ void batch_f128(const int* __restrict__ csr, int j, int rem,
                                           const __half* __restrict__ xwh, int lane,
                                           float2* acc) {
    int s[NB];
#pragma unroll
    for (int k = 0; k < NB; ++k) {
        int jj = MASK ? (j + ((k < rem) ? k : 0)) : (j + k);
        s[k] = csr[jj];
    }
    float2 v[NB];
#pragma unroll
    for (int k = 0; k < NB; ++k) {
        __half2 hv = ((const __half2*)(xwh + (size_t)s[k] * 128))[lane];
        v[k] = __half22float2(hv);
    }
#pragma unroll
    for (int k = 0; k < NB; ++k) {
        float m = (!MASK || (k < rem)) ? 1.0f : 0.0f;
        acc[k & 3].x = fmaf(v[k].x, m, acc[k & 3].x);
        acc[k & 3].y = fmaf(v[k].y, m, acc[k & 3].y);
    }
}

template <int NB, bool MASK>
__device__ __forceinline__ void batch_f64(const int* __restrict__ csr, int j, int rem,
                                          const __half* __restrict__ xwh, int lane,
                                          float* acc) {
    int s[NB];
#pragma unroll
    for (int k = 0; k < NB; ++k) {
        int jj = MASK ? (j + ((k < rem) ? k : 0)) : (j + k);
        s[k] = csr[jj];
    }
    float v[NB];
#pragma unroll
    for (int k = 0; k < NB; ++k)
        v[k] = __half2float(xwh[(size_t)s[k] * 64 + lane]);
#pragma unroll
    for (int k = 0; k < NB; ++k) {
        float m = (!MASK || (k < rem)) ? 1.0f : 0.0f;
        acc[k & 3] = fmaf(v[k], m, acc[k & 3]);
    }
}

// --- fused aggregate: out = dinv[i]*sum_j xwh[src_j] + xw[i]*dinv^2 + b [+relu] ---
// rowptr is clean: row i spans [rowptr[i], rowptr[i+1]); rowptr[n] = E.
template <int F, bool RELU>
__global__ __launch_bounds__(256) void agg_kernel(const int* __restrict__ rowptr,
                                                  const int* __restrict__ csr,
                                                  const float* __restrict__ xw,
                                                  const __half* __restrict__ xwh,
                                                  const float* __restrict__ dinv,
                                                  const float* __restrict__ bias,
                                                  float* __restrict__ out, int n) {
    int wave = threadIdx.x >> 6;
    int lane = threadIdx.x & 63;
    int i0 = blockIdx.x * 4 + wave;
    if (i0 >= n) return;
    // node index is wave-uniform: pin to SGPR so rowptr/csr reads go scalar.
    int i = __builtin_amdgcn_readfirstlane(i0);
    float di = dinv[i];
    float d2 = di * di;
    int j = rowptr[i];
    int end = rowptr[i + 1];
    j = __builtin_amdgcn_readfirstlane(j);
    end = __builtin_amdgcn_readfirstlane(end);

    if constexpr (F == 128) {
        float2 x0 = ((const float2*)(xw + (size_t)i * F))[lane];   // fp32 self-loop
        float2 acc[4];
        acc[0] = acc[1] = acc[2] = acc[3] = make_float2(0.f, 0.f);

        for (; j + 16 <= end; j += 16) batch_f128<16, false>(csr, j, 0, xwh, lane, acc);
        if (j + 8 <= end) { batch_f128<8, false>(csr, j, 0, xwh, lane, acc); j += 8; }
        if (j + 4 <= end) { batch_f128<4, false>(csr, j, 0, xwh, lane, acc); j += 4; }
        int rem = end - j;
        if (rem > 0) batch_f128<4, true>(csr, j, rem, xwh, lane, acc);

        float2 bv = ((const float2*)bias)[lane];
        float2 o;
        o.x = fmaf(di, (acc[0].x + acc[1].x) + (acc[2].x + acc[3].x),
                   fmaf(x0.x, d2, bv.x));
        o.y = fmaf(di, (acc[0].y + acc[1].y) + (acc[2].y + acc[3].y),
                   fmaf(x0.y, d2, bv.y));
        if (RELU) { o.x = fmaxf(o.x, 0.f); o.y = fmaxf(o.y, 0.f); }
        ((float2*)(out + (size_t)i * F))[lane] = o;
    } else {  // F == 64
        float x0 = xw[(size_t)i * F + lane];                        // fp32 self-loop
        float acc[4] = {0.f, 0.f, 0.f, 0.f};

        for (; j + 16 <= end; j += 16) batch_f64<16, false>(csr, j, 0, xwh, lane, acc);
        if (j + 8 <= end) { batch_f64<8, false>(csr, j, 0, xwh, lane, acc); j += 8; }
        if (j + 4 <= end) { batch_f64<4, false>(csr, j, 0, xwh, lane, acc); j += 4; }
        int rem = end - j;
        if (rem > 0) batch_f64<4, true>(csr, j, rem, xwh, lane, acc);

        float o = fmaf(di, (acc[0] + acc[1]) + (acc[2] + acc[3]),
                       fmaf(x0, d2, bias[lane]));
        if (RELU) o = fmaxf(o, 0.f);
        out[(size_t)i * F + lane] = o;
    }
}

extern "C" void kernel_launch(void* const* d_in, const int* in_sizes, int n_in,
                              void* d_out, int out_size, void* d_ws, size_t ws_size,
                              hipStream_t stream) {
    const float* x  = (const float*)d_in[0];
    const int*   ei = (const int*)d_in[1];
    const float* W1 = (const float*)d_in[2];
    const float* b1 = (const float*)d_in[3];
    const float* W2 = (const float*)d_in[4];
    const float* b2 = (const float*)d_in[5];
    const float* W3 = (const float*)d_in[6];
    const float* b3 = (const float*)d_in[7];
    float* out = (float*)d_out;

    int E = in_sizes[1] / 2;
    int n = in_sizes[0] / C_IN;
    const int* src = ei;
    const int* dst = ei + E;
    int nbuk = (n + 255) >> 8;   // 196

    // workspace layout
    float*  A        = (float*)d_ws;                     // [n*128] xw fp32
    float*  B        = A + (size_t)n * C_HID;            // [n*128] h fp32
    __half* Ah       = (__half*)(B + (size_t)n * C_HID); // [n*128] dinv*xw fp16
    int2*   ebuf     = (int2*)(Ah + (size_t)n * C_HID);  // [E] bucketed (src,dst)
    int*    csr      = (int*)(ebuf + E);                 // [E] src, CSR order
    float*  dinv     = (float*)(csr + E);                // [n]
    int*    rowptr   = (int*)(dinv + n);                 // [n+1]
    int*    bukCnt   = rowptr + n + 1;                   // [256]
    int*    bbase    = bukCnt + 256;                     // [nbuk+1]
    int*    cursor   = bbase + 256 + 1;                  // [256]

    // ---- CSR build: bucketed counting sort (once; reused by all 3 layers) ----
    hipMemsetAsync(bukCnt, 0, 256 * sizeof(int), stream);
    buk_hist_kernel<<<PART_BLOCKS, 256, 0, stream>>>(dst, E, bukCnt);
    buk_scan_kernel<<<1, 256, 0, stream>>>(bukCnt, nbuk, E, bbase, cursor);
    buk_place_kernel<<<PART_BLOCKS, 256, 0, stream>>>(src, dst, E, cursor, ebuf);
    buk_fill_kernel<<<nbuk, 256, 0, stream>>>(ebuf, bbase, n, E, rowptr, dinv, csr);

    dim3 g128((n + 63) / 64, C_HID / 64);
    dim3 g64((n + 63) / 64, 1);
    int aggBlocks = (n + 3) / 4;

    // ---- layer 1 ----
    gemm_k128<C_HID><<<g128, 256, 0, stream>>>(x, W1, dinv, A, Ah, n);
    agg_kernel<C_HID, false><<<aggBlocks, 256, 0, stream>>>(rowptr, csr, A, Ah, dinv, b1, B, n);
    // ---- layer 2 ----
    gemm_k128<C_HID><<<g128, 256, 0, stream>>>(B, W2, dinv, A, Ah, n);
    agg_kernel<C_HID, false><<<aggBlocks, 256, 0, stream>>>(rowptr, csr, A, Ah, dinv, b2, B, n);
    // ---- layer 3 ----
    gemm_k128<C_OUT><<<g64, 256, 0, stream>>>(B, W3, dinv, A, Ah, n);
    agg_kernel<C_OUT, true><<<aggBlocks, 256, 0, stream>>>(rowptr, csr, A, Ah, dinv, b3, out, n);
}

// Round 10
// 305.753 us; speedup vs baseline: 1.1443x; 1.0027x over previous
//
#include <hip/hip_runtime.h>
#include <hip/hip_fp16.h>

// GCN 3-layer: N=50000, E=800000, dims 128->128->128->64, fp32 in/out.
// Norm factorization: GEMM epilogue emits xwh = dinv[row]*xw (fp16); agg sums
// xwh rows, scales by dinv[dst], adds fp32 self-loop + bias. CSR = src (4B).
// CSR built by bucketed two-level counting sort (R8; random writes confined to
// L2-local regions). R9: persistent W-resident GEMM, 4 blocks/CU, 2-deep
// register pipeline on X loads (R8 gemm was latency-stalled at VALUBusy 29%).

#define C_IN 128
#define C_HID 128
#define C_OUT 64
#define PART_BLOCKS 256   // blocks in hist/place kernels
#define GEMM_BLOCKS 1024  // persistent gemm grid: 4 blocks/CU

// ---------------- CSR build: bucketed counting sort ----------------
// bucket b = dst >> 8 (256 nodes per bucket, nbuk = ceil(n/256) = 196)

__global__ __launch_bounds__(256) void buk_hist_kernel(const int* __restrict__ dst, int E,
                                                       int* __restrict__ bukCnt) {
    __shared__ int h[256];
    int tid = threadIdx.x;
    h[tid] = 0;
    __syncthreads();
    int chunk = (E + gridDim.x - 1) / gridDim.x;
    int lo = blockIdx.x * chunk;
    int hi = min(lo + chunk, E);
    for (int e = lo + tid; e < hi; e += 256)
        atomicAdd(&h[dst[e] >> 8], 1);
    __syncthreads();
    if (h[tid] > 0) atomicAdd(&bukCnt[tid], h[tid]);
}

__global__ __launch_bounds__(256) void buk_scan_kernel(const int* __restrict__ bukCnt,
                                                       int nbuk, int E,
                                                       int* __restrict__ bbase,
                                                       int* __restrict__ cursor) {
    __shared__ int lds[256];
    int tid = threadIdx.x;
    int v = (tid < nbuk) ? bukCnt[tid] : 0;
    lds[tid] = v;
    __syncthreads();
    for (int off = 1; off < 256; off <<= 1) {
        int u = (tid >= off) ? lds[tid - off] : 0;
        __syncthreads();
        lds[tid] += u;
        __syncthreads();
    }
    int ex = lds[tid] - v;
    if (tid < nbuk) { bbase[tid] = ex; cursor[tid] = ex; }
    if (tid == 0) bbase[nbuk] = E;
}

__global__ __launch_bounds__(256) void buk_place_kernel(const int* __restrict__ src,
                                                        const int* __restrict__ dst, int E,
                                                        int* __restrict__ cursor,
                                                        int2* __restrict__ ebuf) {
    __shared__ int h[256];
    __shared__ int base[256];
    __shared__ int c2[256];
    int tid = threadIdx.x;
    h[tid] = 0;
    c2[tid] = 0;
    __syncthreads();
    int chunk = (E + gridDim.x - 1) / gridDim.x;
    int lo = blockIdx.x * chunk;
    int hi = min(lo + chunk, E);
    for (int e = lo + tid; e < hi; e += 256)
        atomicAdd(&h[dst[e] >> 8], 1);
    __syncthreads();
    int cnt = h[tid];
    if (cnt > 0) base[tid] = atomicAdd(&cursor[tid], cnt);
    __syncthreads();
    for (int e = lo + tid; e < hi; e += 256) {
        int d = dst[e];
        int b = d >> 8;
        int slot = base[b] + atomicAdd(&c2[b], 1);
        ebuf[slot] = make_int2(src[e], d);
    }
}

__global__ __launch_bounds__(256) void buk_fill_kernel(const int2* __restrict__ ebuf,
                                                       const int* __restrict__ bbase,
                                                       int n, int E,
                                                       int* __restrict__ rowptr,
                                                       float* __restrict__ dinv,
                                                       int* __restrict__ csr) {
    __shared__ int deg[256];
    __shared__ int lds[256];
    int b = blockIdx.x;
    int tid = threadIdx.x;
    int lo = bbase[b];
    int hi = bbase[b + 1];
    int node0 = b << 8;
    deg[tid] = 0;
    __syncthreads();
    for (int e = lo + tid; e < hi; e += 256)
        atomicAdd(&deg[ebuf[e].y & 255], 1);
    __syncthreads();
    int d = deg[tid];
    lds[tid] = d;
    __syncthreads();
    for (int off = 1; off < 256; off <<= 1) {
        int u = (tid >= off) ? lds[tid - off] : 0;
        __syncthreads();
        lds[tid] += u;
        __syncthreads();
    }
    int ex = lds[tid] - d;
    int node = node0 + tid;
    if (node < n) {
        rowptr[node] = lo + ex;
        dinv[node] = rsqrtf((float)d + 1.0f);
    }
    if (tid == 0)
        rowptr[min(node0 + 256, n)] = hi;   // next bucket's base / E sentinel
    __syncthreads();
    deg[tid] = lo + ex;                      // running global-slot cursor
    __syncthreads();
    for (int e = lo + tid; e < hi; e += 256) {
        int2 ed = ebuf[e];
        int slot = atomicAdd(&deg[ed.y & 255], 1);
        csr[slot] = ed.x;
    }
}

// ------- GEMM: X[n,128] @ W[128,FOUT] -> Y (fp32), Yh = dinv[row]*Y (fp16) -------
// Persistent: each block stages its 64-col W slice in LDS ONCE, then strides
// over 64-row tiles. X read direct from global with a 2-deep register
// pipeline (load k4+1 while FMA-ing k4). 4 blocks/CU.
template <int FOUT>
__global__ __launch_bounds__(256, 4) void gemm_k128(const float* __restrict__ X,
                                                    const float* __restrict__ W,
                                                    const float* __restrict__ dinv,
                                                    float* __restrict__ Y,
                                                    __half* __restrict__ Yh, int n) {
    constexpr int K = 128;
    constexpr int CT = 64;
    constexpr int MT = 64;
    constexpr int NQ = CT / 4;
    constexpr int RPT = 4;
    constexpr int CTILES = FOUT / CT;   // 2 (F=128) or 1 (F=64)
    __shared__ float Ws[K][CT];         // 32 KB

    int tid = threadIdx.x;
    int ct = (CTILES == 1) ? 0 : (blockIdx.x & (CTILES - 1));
    int col0 = ct * CT;

    // stage W column slice once
#pragma unroll
    for (int i = 0; i < (K * CT / 4) / 256; ++i) {
        int idx = tid + i * 256;
        int k = idx / (CT / 4);
        int c = idx % (CT / 4);
        *(float4*)&Ws[k][c * 4] = *(const float4*)(W + (size_t)k * FOUT + col0 + c * 4);
    }
    __syncthreads();

    int cq = tid % NQ;
    int rg = tid / NQ;
    int nRowTiles = (n + MT - 1) / MT;
    int rtStride = gridDim.x / CTILES;

    for (int rt = blockIdx.x / CTILES; rt < nRowTiles; rt += rtStride) {
        int r0 = rt * MT + rg * RPT;

        const float* xb[RPT];
#pragma unroll
        for (int r = 0; r < RPT; ++r) {
            int gr = r0 + r;
            if (gr > n - 1) gr = n - 1;   // clamp (stores are guarded)
            xb[r] = X + (size_t)gr * K;
        }

        float acc[RPT][4] = {};
        float4 xa[RPT];
#pragma unroll
        for (int r = 0; r < RPT; ++r) xa[r] = *(const float4*)(xb[r]);

#pragma unroll 2
        for (int k4 = 0; k4 < K / 4; ++k4) {
            float4 xn[RPT];
            if (k4 + 1 < K / 4) {
#pragma unroll
                for (int r = 0; r < RPT; ++r)
                    xn[r] = *(const float4*)(xb[r] + (k4 + 1) * 4);
            }
#pragma unroll
            for (int kk = 0; kk < 4; ++kk) {
                float4 w = *(float4*)&Ws[k4 * 4 + kk][cq * 4];
#pragma unroll
                for (int r = 0; r < RPT; ++r) {
                    float xarr[4] = {xa[r].x, xa[r].y, xa[r].z, xa[r].w};
                    float xv = xarr[kk];
                    acc[r][0] = fmaf(xv, w.x, acc[r][0]);
                    acc[r][1] = fmaf(xv, w.y, acc[r][1]);
                    acc[r][2] = fmaf(xv, w.z, acc[r][2]);
                    acc[r][3] = fmaf(xv, w.w, acc[r][3]);
                }
            }
#pragma unroll
            for (int r = 0; r < RPT; ++r) xa[r] = xn[r];
        }
#pragma unroll
        for (int r = 0; r < RPT; ++r) {
            int gr = r0 + r;
            if (gr < n) {
                size_t off = (size_t)gr * FOUT + col0 + cq * 4;
                *(float4*)(Y + off) =
                    make_float4(acc[r][0], acc[r][1], acc[r][2], acc[r][3]);
                float di = dinv[gr];
                __half2 h01 = __floats2half2_rn(acc[r][0] * di, acc[r][1] * di);
                __half2 h23 = __floats2half2_rn(acc[r][2] * di, acc[r][3] * di);
                uint2 pk = make_uint2(*(unsigned int*)&h01, *(unsigned int*)&h23);
                *(uint2*)(Yh + off) = pk;
            }
        }
    }
}

// ---------------- aggregate helpers ----------------
template <int NB, bool MASK>
__device__ __forceinline__ void batch_f128(const int* __restrict__ csr, int j, int rem,
                                           const __half* __restrict__ xwh, int lane,
                                           float2* acc) {
    int s[NB];
#pragma unroll
    for (int k = 0; k < NB; ++k) {
        int jj = MASK ? (j + ((k < rem) ? k : 0)) : (j + k);
        s[k] = csr[jj];
    }
    float2 v[NB];
#pragma unroll
    for (int k = 0; k < NB; ++k) {
        __half2 hv = ((const __half2*)(xwh + (size_t)s[k] * 128))[lane];
        v[k] = __half22float2(hv);
    }
#pragma unroll
    for (int k = 0; k < NB; ++k) {
        float m = (!MASK || (k < rem)) ? 1.0f : 0.0f;
        acc[k & 3].x = fmaf(v[k].x, m, acc[k & 3].x);
        acc[k & 3].y = fmaf(v[k].y, m, acc[k & 3].y);
    }
}

template <int NB, bool MASK>
__device__ __forceinline__ void batch_f64(const int* __restrict__ csr, int j, int rem,
                                          const __half* __restrict__ xwh, int lane,
                                          float* acc) {
    int s[NB];
#pragma unroll
    for (int k = 0; k < NB; ++k) {
        int jj = MASK ? (j + ((k < rem) ? k : 0)) : (j + k);
        s[k] = csr[jj];
    }
    float v[NB];
#pragma unroll
    for (int k = 0; k < NB; ++k)
        v[k] = __half2float(xwh[(size_t)s[k] * 64 + lane]);
#pragma unroll
    for (int k = 0; k < NB; ++k) {
        float m = (!MASK || (k < rem)) ? 1.0f : 0.0f;
        acc[k & 3] = fmaf(v[k], m, acc[k & 3]);
    }
}

// --- fused aggregate: out = dinv[i]*sum_j xwh[src_j] + xw[i]*dinv^2 + b [+relu] ---
// rowptr is clean: row i spans [rowptr[i], rowptr[i+1]); rowptr[n] = E.
template <int F, bool RELU>
__global__ __launch_bounds__(256) void agg_kernel(const int* __restrict__ rowptr,
                                                  const int* __restrict__ csr,
                                                  const float* __restrict__ xw,
                                                  const __half* __restrict__ xwh,
                                                  const float* __restrict__ dinv,
                                                  const float* __restrict__ bias,
                                                  float* __restrict__ out, int n) {
    int wave = threadIdx.x >> 6;
    int lane = threadIdx.x & 63;
    int i0 = blockIdx.x * 4 + wave;
    if (i0 >= n) return;
    int i = __builtin_amdgcn_readfirstlane(i0);
    float di = dinv[i];
    float d2 = di * di;
    int j = rowptr[i];
    int end = rowptr[i + 1];
    j = __builtin_amdgcn_readfirstlane(j);
    end = __builtin_amdgcn_readfirstlane(end);

    if constexpr (F == 128) {
        float2 x0 = ((const float2*)(xw + (size_t)i * F))[lane];   // fp32 self-loop
        float2 acc[4];
        acc[0] = acc[1] = acc[2] = acc[3] = make_float2(0.f, 0.f);

        for (; j + 16 <= end; j += 16) batch_f128<16, false>(csr, j, 0, xwh, lane, acc);
        if (j + 8 <= end) { batch_f128<8, false>(csr, j, 0, xwh, lane, acc); j += 8; }
        if (j + 4 <= end) { batch_f128<4, false>(csr, j, 0, xwh, lane, acc); j += 4; }
        int rem = end - j;
        if (rem > 0) batch_f128<4, true>(csr, j, rem, xwh, lane, acc);

        float2 bv = ((const float2*)bias)[lane];
        float2 o;
        o.x = fmaf(di, (acc[0].x + acc[1].x) + (acc[2].x + acc[3].x),
                   fmaf(x0.x, d2, bv.x));
        o.y = fmaf(di, (acc[0].y + acc[1].y) + (acc[2].y + acc[3].y),
                   fmaf(x0.y, d2, bv.y));
        if (RELU) { o.x = fmaxf(o.x, 0.f); o.y = fmaxf(o.y, 0.f); }
        ((float2*)(out + (size_t)i * F))[lane] = o;
    } else {  // F == 64
        float x0 = xw[(size_t)i * F + lane];                        // fp32 self-loop
        float acc[4] = {0.f, 0.f, 0.f, 0.f};

        for (; j + 16 <= end; j += 16) batch_f64<16, false>(csr, j, 0, xwh, lane, acc);
        if (j + 8 <= end) { batch_f64<8, false>(csr, j, 0, xwh, lane, acc); j += 8; }
        if (j + 4 <= end) { batch_f64<4, false>(csr, j, 0, xwh, lane, acc); j += 4; }
        int rem = end - j;
        if (rem > 0) batch_f64<4, true>(csr, j, rem, xwh, lane, acc);

        float o = fmaf(di, (acc[0] + acc[1]) + (acc[2] + acc[3]),
                       fmaf(x0, d2, bias[lane]));
        if (RELU) o = fmaxf(o, 0.f);
        out[(size_t)i * F + lane] = o;
    }
}

extern "C" void kernel_launch(void* const* d_in, const int* in_sizes, int n_in,
                              void* d_out, int out_size, void* d_ws, size_t ws_size,
                              hipStream_t stream) {
    const float* x  = (const float*)d_in[0];
    const int*   ei = (const int*)d_in[1];
    const float* W1 = (const float*)d_in[2];
    const float* b1 = (const float*)d_in[3];
    const float* W2 = (const float*)d_in[4];
    const float* b2 = (const float*)d_in[5];
    const float* W3 = (const float*)d_in[6];
    const float* b3 = (const float*)d_in[7];
    float* out = (float*)d_out;

    int E = in_sizes[1] / 2;
    int n = in_sizes[0] / C_IN;
    const int* src = ei;
    const int* dst = ei + E;
    int nbuk = (n + 255) >> 8;   // 196

    // workspace layout
    float*  A        = (float*)d_ws;                     // [n*128] xw fp32
    float*  B        = A + (size_t)n * C_HID;            // [n*128] h fp32
    __half* Ah       = (__half*)(B + (size_t)n * C_HID); // [n*128] dinv*xw fp16
    int2*   ebuf     = (int2*)(Ah + (size_t)n * C_HID);  // [E] bucketed (src,dst)
    int*    csr      = (int*)(ebuf + E);                 // [E] src, CSR order
    float*  dinv     = (float*)(csr + E);                // [n]
    int*    rowptr   = (int*)(dinv + n);                 // [n+1]
    int*    bukCnt   = rowptr + n + 1;                   // [256]
    int*    bbase    = bukCnt + 256;                     // [nbuk+1]
    int*    cursor   = bbase + 256 + 1;                  // [256]

    // ---- CSR build: bucketed counting sort (once; reused by all 3 layers) ----
    hipMemsetAsync(bukCnt, 0, 256 * sizeof(int), stream);
    buk_hist_kernel<<<PART_BLOCKS, 256, 0, stream>>>(dst, E, bukCnt);
    buk_scan_kernel<<<1, 256, 0, stream>>>(bukCnt, nbuk, E, bbase, cursor);
    buk_place_kernel<<<PART_BLOCKS, 256, 0, stream>>>(src, dst, E, cursor, ebuf);
    buk_fill_kernel<<<nbuk, 256, 0, stream>>>(ebuf, bbase, n, E, rowptr, dinv, csr);

    int aggBlocks = (n + 3) / 4;

    // ---- layer 1 ----
    gemm_k128<C_HID><<<GEMM_BLOCKS, 256, 0, stream>>>(x, W1, dinv, A, Ah, n);
    agg_kernel<C_HID, false><<<aggBlocks, 256, 0, stream>>>(rowptr, csr, A, Ah, dinv, b1, B, n);
    // ---- layer 2 ----
    gemm_k128<C_HID><<<GEMM_BLOCKS, 256, 0, stream>>>(B, W2, dinv, A, Ah, n);
    agg_kernel<C_HID, false><<<aggBlocks, 256, 0, stream>>>(rowptr, csr, A, Ah, dinv, b2, B, n);
    // ---- layer 3 ----
    gemm_k128<C_OUT><<<GEMM_BLOCKS, 256, 0, stream>>>(B, W3, dinv, A, Ah, n);
    agg_kernel<C_OUT, true><<<aggBlocks, 256, 0, stream>>>(rowptr, csr, A, Ah, dinv, b3, out, n);
}

// Round 11
// 293.078 us; speedup vs baseline: 1.1938x; 1.0432x over previous
//
#include <hip/hip_runtime.h>
#include <hip/hip_fp16.h>

// GCN 3-layer: N=50000, E=800000, dims 128->128->128->64, fp32 in/out.
// R10: GEMM on matrix cores via bf16x3 split (x=hi+lo, W=Whi+Wlo;
// x@W ~= hi@Whi + hi@Wlo + lo@Whi, fp32 MFMA accum; err ~2^-16).
// mfma_f32_16x16x32_bf16 layouts (m89-verified): A lane l: row=l&15,
// k=(l>>4)*8+j; B: col=l&15 same k; C/D: row=(l>>4)*4+r, col=l&15.
// agg epilogue emits next layer's bf16 hi/lo; split_x seeds layer 1.
// CSR bucketed counting sort + fp16 gather agg unchanged (R8/R9 passing).

#define C_IN 128
#define C_HID 128
#define C_OUT 64
#define PART_BLOCKS 256

typedef __attribute__((ext_vector_type(8))) short bf16x8;
typedef __attribute__((ext_vector_type(4))) float f32x4;

__device__ __forceinline__ unsigned short bf16_rne(float f) {
    unsigned u = __float_as_uint(f);
    unsigned r = u + 0x7FFFu + ((u >> 16) & 1u);
    return (unsigned short)(r >> 16);
}
__device__ __forceinline__ float bf16_f(unsigned short h) {
    return __uint_as_float(((unsigned)h) << 16);
}

// ---------------- CSR build: bucketed counting sort (R8) ----------------

__global__ __launch_bounds__(256) void buk_hist_kernel(const int* __restrict__ dst, int E,
                                                       int* __restrict__ bukCnt) {
    __shared__ int h[256];
    int tid = threadIdx.x;
    h[tid] = 0;
    __syncthreads();
    int chunk = (E + gridDim.x - 1) / gridDim.x;
    int lo = blockIdx.x * chunk;
    int hi = min(lo + chunk, E);
    for (int e = lo + tid; e < hi; e += 256)
        atomicAdd(&h[dst[e] >> 8], 1);
    __syncthreads();
    if (h[tid] > 0) atomicAdd(&bukCnt[tid], h[tid]);
}

__global__ __launch_bounds__(256) void buk_scan_kernel(const int* __restrict__ bukCnt,
                                                       int nbuk, int E,
                                                       int* __restrict__ bbase,
                                                       int* __restrict__ cursor) {
    __shared__ int lds[256];
    int tid = threadIdx.x;
    int v = (tid < nbuk) ? bukCnt[tid] : 0;
    lds[tid] = v;
    __syncthreads();
    for (int off = 1; off < 256; off <<= 1) {
        int u = (tid >= off) ? lds[tid - off] : 0;
        __syncthreads();
        lds[tid] += u;
        __syncthreads();
    }
    int ex = lds[tid] - v;
    if (tid < nbuk) { bbase[tid] = ex; cursor[tid] = ex; }
    if (tid == 0) bbase[nbuk] = E;
}

__global__ __launch_bounds__(256) void buk_place_kernel(const int* __restrict__ src,
                                                        const int* __restrict__ dst, int E,
                                                        int* __restrict__ cursor,
                                                        int2* __restrict__ ebuf) {
    __shared__ int h[256];
    __shared__ int base[256];
    __shared__ int c2[256];
    int tid = threadIdx.x;
    h[tid] = 0;
    c2[tid] = 0;
    __syncthreads();
    int chunk = (E + gridDim.x - 1) / gridDim.x;
    int lo = blockIdx.x * chunk;
    int hi = min(lo + chunk, E);
    for (int e = lo + tid; e < hi; e += 256)
        atomicAdd(&h[dst[e] >> 8], 1);
    __syncthreads();
    int cnt = h[tid];
    if (cnt > 0) base[tid] = atomicAdd(&cursor[tid], cnt);
    __syncthreads();
    for (int e = lo + tid; e < hi; e += 256) {
        int d = dst[e];
        int b = d >> 8;
        int slot = base[b] + atomicAdd(&c2[b], 1);
        ebuf[slot] = make_int2(src[e], d);
    }
}

__global__ __launch_bounds__(256) void buk_fill_kernel(const int2* __restrict__ ebuf,
                                                       const int* __restrict__ bbase,
                                                       int n, int E,
                                                       int* __restrict__ rowptr,
                                                       float* __restrict__ dinv,
                                                       int* __restrict__ csr) {
    __shared__ int deg[256];
    __shared__ int lds[256];
    int b = blockIdx.x;
    int tid = threadIdx.x;
    int lo = bbase[b];
    int hi = bbase[b + 1];
    int node0 = b << 8;
    deg[tid] = 0;
    __syncthreads();
    for (int e = lo + tid; e < hi; e += 256)
        atomicAdd(&deg[ebuf[e].y & 255], 1);
    __syncthreads();
    int d = deg[tid];
    lds[tid] = d;
    __syncthreads();
    for (int off = 1; off < 256; off <<= 1) {
        int u = (tid >= off) ? lds[tid - off] : 0;
        __syncthreads();
        lds[tid] += u;
        __syncthreads();
    }
    int ex = lds[tid] - d;
    int node = node0 + tid;
    if (node < n) {
        rowptr[node] = lo + ex;
        dinv[node] = rsqrtf((float)d + 1.0f);
    }
    if (tid == 0)
        rowptr[min(node0 + 256, n)] = hi;
    __syncthreads();
    deg[tid] = lo + ex;
    __syncthreads();
    for (int e = lo + tid; e < hi; e += 256) {
        int2 ed = ebuf[e];
        int slot = atomicAdd(&deg[ed.y & 255], 1);
        csr[slot] = ed.x;
    }
}

// ---------------- split x (fp32 -> bf16 hi/lo), layer-1 seed ----------------
__global__ __launch_bounds__(256) void split_kernel(const float* __restrict__ X,
                                                    unsigned short* __restrict__ Hi,
                                                    unsigned short* __restrict__ Lo,
                                                    int total4) {
    int g = blockIdx.x * blockDim.x + threadIdx.x;
    if (g >= total4) return;
    float4 v = ((const float4*)X)[g];
    float vv[4] = {v.x, v.y, v.z, v.w};
    unsigned short h[4], l[4];
#pragma unroll
    for (int i = 0; i < 4; ++i) {
        h[i] = bf16_rne(vv[i]);
        l[i] = bf16_rne(vv[i] - bf16_f(h[i]));
    }
    uint2 ph = make_uint2((unsigned)h[0] | ((unsigned)h[1] << 16),
                          (unsigned)h[2] | ((unsigned)h[3] << 16));
    uint2 pl = make_uint2((unsigned)l[0] | ((unsigned)l[1] << 16),
                          (unsigned)l[2] | ((unsigned)l[3] << 16));
    ((uint2*)Hi)[g] = ph;
    ((uint2*)Lo)[g] = pl;
}

// ------- MFMA GEMM: (Xhi+Xlo)[n,128] @ W[128,FOUT] -> Y fp32, Yh = dinv*Y fp16 -------
// Block = 4 waves = 64 rows x 64 cols. W hi/lo staged once into LDS in frag
// order, hoisted to VGPRs. 48 mfma_f32_16x16x32_bf16 per row-tile per wave.
template <int FOUT>
__global__ __launch_bounds__(256, 2) void gemm_mfma(const unsigned short* __restrict__ Xhi,
                                                    const unsigned short* __restrict__ Xlo,
                                                    const float* __restrict__ W,
                                                    const float* __restrict__ dinv,
                                                    float* __restrict__ Y,
                                                    __half* __restrict__ Yh, int n) {
    constexpr int CT = 64;
    constexpr int CTILES = FOUT / CT;   // 2 (F=128) or 1 (F=64)
    __shared__ unsigned short Bf[2][4][4][64][8];   // 32 KB: [hi/lo][kt][nt][lane][j]

    int tid = threadIdx.x;
    int wv = tid >> 6, lane = tid & 63;
    int ct = (CTILES == 1) ? 0 : (blockIdx.x % CTILES);
    int rt = blockIdx.x / CTILES;
    int col0 = ct * CT;
    int row0 = rt * 64 + wv * 16;

    // issue A loads early (hide under W staging + barrier)
    int rA = row0 + (lane & 15);
    if (rA > n - 1) rA = n - 1;
    const unsigned short* ph = Xhi + (size_t)rA * 128 + ((lane >> 4) * 8);
    const unsigned short* pl = Xlo + (size_t)rA * 128 + ((lane >> 4) * 8);
    bf16x8 ah[4], al[4];
#pragma unroll
    for (int kt = 0; kt < 4; ++kt) {
        ah[kt] = *(const bf16x8*)(ph + kt * 32);
        al[kt] = *(const bf16x8*)(pl + kt * 32);
    }

    // stage W -> hi/lo frags in LDS (each thread packs 8 frag-lane rows of 8)
#pragma unroll
    for (int i = 0; i < 8; ++i) {
        int rid = tid + i * 256;         // 0..2047
        int set = rid >> 10;             // 0=hi 1=lo
        int rem = rid & 1023;
        int fr = rem >> 6;               // kt*4+nt
        int ln = rem & 63;
        int kt = fr >> 2, nt = fr & 3;
        int kbase = kt * 32 + (ln >> 4) * 8;
        int cc = col0 + nt * 16 + (ln & 15);
        unsigned short tmp[8];
#pragma unroll
        for (int j = 0; j < 8; ++j) {
            float w = W[(size_t)(kbase + j) * FOUT + cc];
            unsigned short hh = bf16_rne(w);
            tmp[j] = (set == 0) ? hh : bf16_rne(w - bf16_f(hh));
        }
        *(bf16x8*)&Bf[set][kt][nt][ln][0] = *(bf16x8*)tmp;
    }
    __syncthreads();

    // hoist B frags to VGPRs
    bf16x8 bh[4][4], bl[4][4];
#pragma unroll
    for (int kt = 0; kt < 4; ++kt)
#pragma unroll
        for (int nt = 0; nt < 4; ++nt) {
            bh[kt][nt] = *(const bf16x8*)&Bf[0][kt][nt][lane][0];
            bl[kt][nt] = *(const bf16x8*)&Bf[1][kt][nt][lane][0];
        }

    f32x4 acc[4];
#pragma unroll
    for (int nt = 0; nt < 4; ++nt) acc[nt] = (f32x4){0.f, 0.f, 0.f, 0.f};

#pragma unroll
    for (int kt = 0; kt < 4; ++kt)
#pragma unroll
        for (int nt = 0; nt < 4; ++nt) {
            acc[nt] = __builtin_amdgcn_mfma_f32_16x16x32_bf16(ah[kt], bh[kt][nt], acc[nt], 0, 0, 0);
            acc[nt] = __builtin_amdgcn_mfma_f32_16x16x32_bf16(ah[kt], bl[kt][nt], acc[nt], 0, 0, 0);
            acc[nt] = __builtin_amdgcn_mfma_f32_16x16x32_bf16(al[kt], bh[kt][nt], acc[nt], 0, 0, 0);
        }

    // epilogue: C row=(lane>>4)*4+r, col=nt*16+(lane&15)
#pragma unroll
    for (int r = 0; r < 4; ++r) {
        int grow = row0 + (lane >> 4) * 4 + r;
        if (grow < n) {
            float di = dinv[grow];
#pragma unroll
            for (int nt = 0; nt < 4; ++nt) {
                float v = acc[nt][r];
                size_t off = (size_t)grow * FOUT + col0 + nt * 16 + (lane & 15);
                Y[off] = v;
                Yh[off] = __float2half(v * di);
            }
        }
    }
}

// ---------------- aggregate helpers (fp16 gathers, R6/R7) ----------------
template <int NB, bool MASK>
__device__ __forceinline__ void batch_f128(const int* __restrict__ csr, int j, int rem,
                                           const __half* __restrict__ xwh, int lane,
                                           float2* acc) {
    int s[NB];
#pragma unroll
    for (int k = 0; k < NB; ++k) {
        int jj = MASK ? (j + ((k < rem) ? k : 0)) : (j + k);
        s[k] = csr[jj];
    }
    float2 v[NB];
#pragma unroll
    for (int k = 0; k < NB; ++k) {
        __half2 hv = ((const __half2*)(xwh + (size_t)s[k] * 128))[lane];
        v[k] = __half22float2(hv);
    }
#pragma unroll
    for (int k = 0; k < NB; ++k) {
        float m = (!MASK || (k < rem)) ? 1.0f : 0.0f;
        acc[k & 3].x = fmaf(v[k].x, m, acc[k & 3].x);
        acc[k & 3].y = fmaf(v[k].y, m, acc[k & 3].y);
    }
}

template <int NB, bool MASK>
__device__ __forceinline__ void batch_f64(const int* __restrict__ csr, int j, int rem,
                                          const __half* __restrict__ xwh, int lane,
                                          float* acc) {
    int s[NB];
#pragma unroll
    for (int k = 0; k < NB; ++k) {
        int jj = MASK ? (j + ((k < rem) ? k : 0)) : (j + k);
        s[k] = csr[jj];
    }
    float v[NB];
#pragma unroll
    for (int k = 0; k < NB; ++k)
        v[k] = __half2float(xwh[(size_t)s[k] * 64 + lane]);
#pragma unroll
    for (int k = 0; k < NB; ++k) {
        float m = (!MASK || (k < rem)) ? 1.0f : 0.0f;
        acc[k & 3] = fmaf(v[k], m, acc[k & 3]);
    }
}

// --- fused aggregate: o = dinv[i]*sum_j xwh[src_j] + xw[i]*dinv^2 + b ---
// MODE 0 (F=128): write bf16 hi/lo pair (next gemm's A operand), no relu.
// MODE 1 (F=64): write fp32 + relu (final output).
template <int F, int MODE>
__global__ __launch_bounds__(256) void agg_kernel(const int* __restrict__ rowptr,
                                                  const int* __restrict__ csr,
                                                  const float* __restrict__ xw,
                                                  const __half* __restrict__ xwh,
                                                  const float* __restrict__ dinv,
                                                  const float* __restrict__ bias,
                                                  float* __restrict__ out,
                                                  unsigned short* __restrict__ outHi,
                                                  unsigned short* __restrict__ outLo,
                                                  int n) {
    int wave = threadIdx.x >> 6;
    int lane = threadIdx.x & 63;
    int i0 = blockIdx.x * 4 + wave;
    if (i0 >= n) return;
    int i = __builtin_amdgcn_readfirstlane(i0);
    float di = dinv[i];
    float d2 = di * di;
    int j = rowptr[i];
    int end = rowptr[i + 1];
    j = __builtin_amdgcn_readfirstlane(j);
    end = __builtin_amdgcn_readfirstlane(end);

    if constexpr (F == 128) {
        float2 x0 = ((const float2*)(xw + (size_t)i * F))[lane];
        float2 acc[4];
        acc[0] = acc[1] = acc[2] = acc[3] = make_float2(0.f, 0.f);

        for (; j + 16 <= end; j += 16) batch_f128<16, false>(csr, j, 0, xwh, lane, acc);
        if (j + 8 <= end) { batch_f128<8, false>(csr, j, 0, xwh, lane, acc); j += 8; }
        if (j + 4 <= end) { batch_f128<4, false>(csr, j, 0, xwh, lane, acc); j += 4; }
        int rem = end - j;
        if (rem > 0) batch_f128<4, true>(csr, j, rem, xwh, lane, acc);

        float2 bv = ((const float2*)bias)[lane];
        float ox = fmaf(di, (acc[0].x + acc[1].x) + (acc[2].x + acc[3].x),
                        fmaf(x0.x, d2, bv.x));
        float oy = fmaf(di, (acc[0].y + acc[1].y) + (acc[2].y + acc[3].y),
                        fmaf(x0.y, d2, bv.y));
        unsigned short h0 = bf16_rne(ox);
        unsigned short l0 = bf16_rne(ox - bf16_f(h0));
        unsigned short h1 = bf16_rne(oy);
        unsigned short l1 = bf16_rne(oy - bf16_f(h1));
        ((unsigned*)(outHi + (size_t)i * F))[lane] = (unsigned)h0 | ((unsigned)h1 << 16);
        ((unsigned*)(outLo + (size_t)i * F))[lane] = (unsigned)l0 | ((unsigned)l1 << 16);
    } else {  // F == 64, final layer
        float x0 = xw[(size_t)i * F + lane];
        float acc[4] = {0.f, 0.f, 0.f, 0.f};

        for (; j + 16 <= end; j += 16) batch_f64<16, false>(csr, j, 0, xwh, lane, acc);
        if (j + 8 <= end) { batch_f64<8, false>(csr, j, 0, xwh, lane, acc); j += 8; }
        if (j + 4 <= end) { batch_f64<4, false>(csr, j, 0, xwh, lane, acc); j += 4; }
        int rem = end - j;
        if (rem > 0) batch_f64<4, true>(csr, j, rem, xwh, lane, acc);

        float o = fmaf(di, (acc[0] + acc[1]) + (acc[2] + acc[3]),
                       fmaf(x0, d2, bias[lane]));
        o = fmaxf(o, 0.f);
        out[(size_t)i * F + lane] = o;
    }
}

extern "C" void kernel_launch(void* const* d_in, const int* in_sizes, int n_in,
                              void* d_out, int out_size, void* d_ws, size_t ws_size,
                              hipStream_t stream) {
    const float* x  = (const float*)d_in[0];
    const int*   ei = (const int*)d_in[1];
    const float* W1 = (const float*)d_in[2];
    const float* b1 = (const float*)d_in[3];
    const float* W2 = (const float*)d_in[4];
    const float* b2 = (const float*)d_in[5];
    const float* W3 = (const float*)d_in[6];
    const float* b3 = (const float*)d_in[7];
    float* out = (float*)d_out;

    int E = in_sizes[1] / 2;
    int n = in_sizes[0] / C_IN;
    const int* src = ei;
    const int* dst = ei + E;
    int nbuk = (n + 255) >> 8;

    // workspace layout (16B-aligned segments)
    float*          A    = (float*)d_ws;                        // [n*128] gemm Y fp32
    __half*         Ah   = (__half*)(A + (size_t)n * C_HID);    // [n*128] dinv*Y fp16
    unsigned short* Bhi  = (unsigned short*)(Ah + (size_t)n * C_HID); // [n*128] bf16 hi
    unsigned short* Blo  = Bhi + (size_t)n * C_HID;             // [n*128] bf16 lo
    int2*           ebuf = (int2*)(Blo + (size_t)n * C_HID);    // [E]
    int*            csr  = (int*)(ebuf + E);                    // [E]
    float*          dinv = (float*)(csr + E);                   // [n]
    int*            rowptr = (int*)(dinv + n);                  // [n+1]
    int*            bukCnt = rowptr + n + 1;                    // [256]
    int*            bbase  = bukCnt + 256;                      // [nbuk+1]
    int*            cursor = bbase + 256 + 1;                   // [256]

    // ---- CSR build ----
    hipMemsetAsync(bukCnt, 0, 256 * sizeof(int), stream);
    buk_hist_kernel<<<PART_BLOCKS, 256, 0, stream>>>(dst, E, bukCnt);
    buk_scan_kernel<<<1, 256, 0, stream>>>(bukCnt, nbuk, E, bbase, cursor);
    buk_place_kernel<<<PART_BLOCKS, 256, 0, stream>>>(src, dst, E, cursor, ebuf);
    buk_fill_kernel<<<nbuk, 256, 0, stream>>>(ebuf, bbase, n, E, rowptr, dinv, csr);

    // ---- split layer-1 input into bf16 hi/lo ----
    int total4 = n * C_IN / 4;
    split_kernel<<<(total4 + 255) / 256, 256, 0, stream>>>(x, Bhi, Blo, total4);

    int aggBlocks = (n + 3) / 4;
    int rowTiles = (n + 63) / 64;   // 782

    // ---- layer 1 ----
    gemm_mfma<C_HID><<<rowTiles * 2, 256, 0, stream>>>(Bhi, Blo, W1, dinv, A, Ah, n);
    agg_kernel<C_HID, 0><<<aggBlocks, 256, 0, stream>>>(rowptr, csr, A, Ah, dinv, b1,
                                                        nullptr, Bhi, Blo, n);
    // ---- layer 2 ----
    gemm_mfma<C_HID><<<rowTiles * 2, 256, 0, stream>>>(Bhi, Blo, W2, dinv, A, Ah, n);
    agg_kernel<C_HID, 0><<<aggBlocks, 256, 0, stream>>>(rowptr, csr, A, Ah, dinv, b2,
                                                        nullptr, Bhi, Blo, n);
    // ---- layer 3 ----
    gemm_mfma<C_OUT><<<rowTiles, 256, 0, stream>>>(Bhi, Blo, W3, dinv, A, Ah, n);
    agg_kernel<C_OUT, 1><<<aggBlocks, 256, 0, stream>>>(rowptr, csr, A, Ah, dinv, b3,
                                                        out, nullptr, nullptr, n);
}

// Round 12
// 278.256 us; speedup vs baseline: 1.2574x; 1.0533x over previous
//
#include <hip/hip_runtime.h>
#include <hip/hip_fp16.h>

// GCN 3-layer: N=50000, E=800000, dims 128->128->128->64, fp32 in/out.
// GEMM on matrix cores via bf16x3 split (x=hi+lo, W=Whi+Wlo;
// x@W ~= hi@Whi + hi@Wlo + lo@Whi, fp32 MFMA accum).
// R11: W pre-split ONCE into frag-ordered bf16 hi/lo buffers (160KB,
// L2-resident); gemm is LDS-free, barrier-free, loads B frags coalesced.
// mfma_f32_16x16x32_bf16 layouts (m89-verified): A lane l: row=l&15,
// k=(l>>4)*8+j; B: col=l&15 same k; C/D: row=(l>>4)*4+r, col=l&15.
// agg epilogue emits next layer's bf16 hi/lo; CSR bucketed sort (R8).

#define C_IN 128
#define C_HID 128
#define C_OUT 64
#define PART_BLOCKS 256

typedef __attribute__((ext_vector_type(8))) short bf16x8;
typedef __attribute__((ext_vector_type(4))) float f32x4;

__device__ __forceinline__ unsigned short bf16_rne(float f) {
    unsigned u = __float_as_uint(f);
    unsigned r = u + 0x7FFFu + ((u >> 16) & 1u);
    return (unsigned short)(r >> 16);
}
__device__ __forceinline__ float bf16_f(unsigned short h) {
    return __uint_as_float(((unsigned)h) << 16);
}

// ---------------- CSR build: bucketed counting sort (R8) ----------------

__global__ __launch_bounds__(256) void buk_hist_kernel(const int* __restrict__ dst, int E,
                                                       int* __restrict__ bukCnt) {
    __shared__ int h[256];
    int tid = threadIdx.x;
    h[tid] = 0;
    __syncthreads();
    int chunk = (E + gridDim.x - 1) / gridDim.x;
    int lo = blockIdx.x * chunk;
    int hi = min(lo + chunk, E);
    for (int e = lo + tid; e < hi; e += 256)
        atomicAdd(&h[dst[e] >> 8], 1);
    __syncthreads();
    if (h[tid] > 0) atomicAdd(&bukCnt[tid], h[tid]);
}

__global__ __launch_bounds__(256) void buk_scan_kernel(const int* __restrict__ bukCnt,
                                                       int nbuk, int E,
                                                       int* __restrict__ bbase,
                                                       int* __restrict__ cursor) {
    __shared__ int lds[256];
    int tid = threadIdx.x;
    int v = (tid < nbuk) ? bukCnt[tid] : 0;
    lds[tid] = v;
    __syncthreads();
    for (int off = 1; off < 256; off <<= 1) {
        int u = (tid >= off) ? lds[tid - off] : 0;
        __syncthreads();
        lds[tid] += u;
        __syncthreads();
    }
    int ex = lds[tid] - v;
    if (tid < nbuk) { bbase[tid] = ex; cursor[tid] = ex; }
    if (tid == 0) bbase[nbuk] = E;
}

__global__ __launch_bounds__(256) void buk_place_kernel(const int* __restrict__ src,
                                                        const int* __restrict__ dst, int E,
                                                        int* __restrict__ cursor,
                                                        int2* __restrict__ ebuf) {
    __shared__ int h[256];
    __shared__ int base[256];
    __shared__ int c2[256];
    int tid = threadIdx.x;
    h[tid] = 0;
    c2[tid] = 0;
    __syncthreads();
    int chunk = (E + gridDim.x - 1) / gridDim.x;
    int lo = blockIdx.x * chunk;
    int hi = min(lo + chunk, E);
    for (int e = lo + tid; e < hi; e += 256)
        atomicAdd(&h[dst[e] >> 8], 1);
    __syncthreads();
    int cnt = h[tid];
    if (cnt > 0) base[tid] = atomicAdd(&cursor[tid], cnt);
    __syncthreads();
    for (int e = lo + tid; e < hi; e += 256) {
        int d = dst[e];
        int b = d >> 8;
        int slot = base[b] + atomicAdd(&c2[b], 1);
        ebuf[slot] = make_int2(src[e], d);
    }
}

__global__ __launch_bounds__(256) void buk_fill_kernel(const int2* __restrict__ ebuf,
                                                       const int* __restrict__ bbase,
                                                       int n, int E,
                                                       int* __restrict__ rowptr,
                                                       float* __restrict__ dinv,
                                                       int* __restrict__ csr) {
    __shared__ int deg[256];
    __shared__ int lds[256];
    int b = blockIdx.x;
    int tid = threadIdx.x;
    int lo = bbase[b];
    int hi = bbase[b + 1];
    int node0 = b << 8;
    deg[tid] = 0;
    __syncthreads();
    for (int e = lo + tid; e < hi; e += 256)
        atomicAdd(&deg[ebuf[e].y & 255], 1);
    __syncthreads();
    int d = deg[tid];
    lds[tid] = d;
    __syncthreads();
    for (int off = 1; off < 256; off <<= 1) {
        int u = (tid >= off) ? lds[tid - off] : 0;
        __syncthreads();
        lds[tid] += u;
        __syncthreads();
    }
    int ex = lds[tid] - d;
    int node = node0 + tid;
    if (node < n) {
        rowptr[node] = lo + ex;
        dinv[node] = rsqrtf((float)d + 1.0f);
    }
    if (tid == 0)
        rowptr[min(node0 + 256, n)] = hi;
    __syncthreads();
    deg[tid] = lo + ex;
    __syncthreads();
    for (int e = lo + tid; e < hi; e += 256) {
        int2 ed = ebuf[e];
        int slot = atomicAdd(&deg[ed.y & 255], 1);
        csr[slot] = ed.x;
    }
}

// ---------------- split x (fp32 -> bf16 hi/lo), layer-1 seed ----------------
__global__ __launch_bounds__(256) void split_kernel(const float* __restrict__ X,
                                                    unsigned short* __restrict__ Hi,
                                                    unsigned short* __restrict__ Lo,
                                                    int total4) {
    int g = blockIdx.x * blockDim.x + threadIdx.x;
    if (g >= total4) return;
    float4 v = ((const float4*)X)[g];
    float vv[4] = {v.x, v.y, v.z, v.w};
    unsigned short h[4], l[4];
#pragma unroll
    for (int i = 0; i < 4; ++i) {
        h[i] = bf16_rne(vv[i]);
        l[i] = bf16_rne(vv[i] - bf16_f(h[i]));
    }
    uint2 ph = make_uint2((unsigned)h[0] | ((unsigned)h[1] << 16),
                          (unsigned)h[2] | ((unsigned)h[3] << 16));
    uint2 pl = make_uint2((unsigned)l[0] | ((unsigned)l[1] << 16),
                          (unsigned)l[2] | ((unsigned)l[3] << 16));
    ((uint2*)Hi)[g] = ph;
    ((uint2*)Lo)[g] = pl;
}

// ---- W pre-split into MFMA-frag-ordered bf16 hi/lo (all 3 layers, once) ----
// Frag g = ct*1024 + kt*256 + nt*64 + lane; value j (0..7) =
//   W[(kt*32+(lane>>4)*8+j)*FOUT + ct*64+nt*16+(lane&15)].
// Region layout (ushort counts): L1 hi 16384 | L1 lo 16384 | L2 hi 16384 |
//   L2 lo 16384 | L3 hi 8192 | L3 lo 8192.
__global__ __launch_bounds__(256) void wsplit_all_kernel(const float* __restrict__ W1,
                                                         const float* __restrict__ W2,
                                                         const float* __restrict__ W3,
                                                         unsigned short* __restrict__ Wf) {
    int g = blockIdx.x * 256 + threadIdx.x;   // 0..5119
    const float* W;
    int FOUT, NF, base;
    if (g < 2048)      { W = W1; FOUT = 128; NF = 2048; base = 0;     }
    else if (g < 4096) { W = W2; FOUT = 128; NF = 2048; base = 32768; g -= 2048; }
    else if (g < 5120) { W = W3; FOUT = 64;  NF = 1024; base = 65536; g -= 4096; }
    else return;
    int lane = g & 63;
    int nt = (g >> 6) & 3;
    int kt = (g >> 8) & 3;
    int ct = g >> 10;
    int kbase = kt * 32 + (lane >> 4) * 8;
    int cc = ct * 64 + nt * 16 + (lane & 15);
    unsigned short hi8[8], lo8[8];
#pragma unroll
    for (int j = 0; j < 8; ++j) {
        float w = W[(size_t)(kbase + j) * FOUT + cc];
        hi8[j] = bf16_rne(w);
        lo8[j] = bf16_rne(w - bf16_f(hi8[j]));
    }
    *(bf16x8*)&Wf[(size_t)(base + g * 8)] = *(bf16x8*)hi8;
    *(bf16x8*)&Wf[(size_t)(base + NF * 8 + g * 8)] = *(bf16x8*)lo8;
}

// ------- MFMA GEMM: (Xhi+Xlo)[n,128] @ W[128,FOUT] -> Y fp32, Yh = dinv*Y fp16 -------
// LDS-free, barrier-free: B frags read coalesced from frag-ordered Wf (L2-hit).
// Block = 4 waves = 64 rows x 64 cols; 48 mfma_f32_16x16x32_bf16 per wave.
template <int FOUT>
__global__ __launch_bounds__(256, 3) void gemm_mfma(const unsigned short* __restrict__ Xhi,
                                                    const unsigned short* __restrict__ Xlo,
                                                    const unsigned short* __restrict__ WfHi,
                                                    const unsigned short* __restrict__ WfLo,
                                                    const float* __restrict__ dinv,
                                                    float* __restrict__ Y,
                                                    __half* __restrict__ Yh, int n) {
    constexpr int CTILES = FOUT / 64;   // 2 (F=128) or 1 (F=64)
    int tid = threadIdx.x;
    int wv = tid >> 6, lane = tid & 63;
    int ct = (CTILES == 1) ? 0 : (blockIdx.x % CTILES);
    int rt = blockIdx.x / CTILES;
    int col0 = ct * 64;
    int row0 = rt * 64 + wv * 16;

    // A frags: lane l holds row l&15, k = (l>>4)*8 + j (+32 per kt)
    int rA = row0 + (lane & 15);
    if (rA > n - 1) rA = n - 1;
    const unsigned short* ph = Xhi + (size_t)rA * 128 + ((lane >> 4) * 8);
    const unsigned short* pl = Xlo + (size_t)rA * 128 + ((lane >> 4) * 8);
    bf16x8 ah[4], al[4];
#pragma unroll
    for (int kt = 0; kt < 4; ++kt) {
        ah[kt] = *(const bf16x8*)(ph + kt * 32);
        al[kt] = *(const bf16x8*)(pl + kt * 32);
    }

    const bf16x8* bhp = (const bf16x8*)WfHi + (size_t)ct * 1024 + lane;
    const bf16x8* blp = (const bf16x8*)WfLo + (size_t)ct * 1024 + lane;

    f32x4 acc[4];
#pragma unroll
    for (int nt = 0; nt < 4; ++nt) acc[nt] = (f32x4){0.f, 0.f, 0.f, 0.f};

#pragma unroll
    for (int kt = 0; kt < 4; ++kt) {
        bf16x8 bh[4], bl[4];
#pragma unroll
        for (int nt = 0; nt < 4; ++nt) {
            bh[nt] = bhp[(kt * 4 + nt) * 64];
            bl[nt] = blp[(kt * 4 + nt) * 64];
        }
#pragma unroll
        for (int nt = 0; nt < 4; ++nt) {
            acc[nt] = __builtin_amdgcn_mfma_f32_16x16x32_bf16(ah[kt], bh[nt], acc[nt], 0, 0, 0);
            acc[nt] = __builtin_amdgcn_mfma_f32_16x16x32_bf16(ah[kt], bl[nt], acc[nt], 0, 0, 0);
            acc[nt] = __builtin_amdgcn_mfma_f32_16x16x32_bf16(al[kt], bh[nt], acc[nt], 0, 0, 0);
        }
    }

    // epilogue: C row=(lane>>4)*4+r, col=nt*16+(lane&15)
#pragma unroll
    for (int r = 0; r < 4; ++r) {
        int grow = row0 + (lane >> 4) * 4 + r;
        if (grow < n) {
            float di = dinv[grow];
#pragma unroll
            for (int nt = 0; nt < 4; ++nt) {
                float v = acc[nt][r];
                size_t off = (size_t)grow * FOUT + col0 + nt * 16 + (lane & 15);
                Y[off] = v;
                Yh[off] = __float2half(v * di);
            }
        }
    }
}

// ---------------- aggregate helpers (fp16 gathers) ----------------
template <int NB, bool MASK>
__device__ __forceinline__ void batch_f128(const int* __restrict__ csr, int j, int rem,
                                           const __half* __restrict__ xwh, int lane,
                                           float2* acc) {
    int s[NB];
#pragma unroll
    for (int k = 0; k < NB; ++k) {
        int jj = MASK ? (j + ((k < rem) ? k : 0)) : (j + k);
        s[k] = csr[jj];
    }
    float2 v[NB];
#pragma unroll
    for (int k = 0; k < NB; ++k) {
        __half2 hv = ((const __half2*)(xwh + (size_t)s[k] * 128))[lane];
        v[k] = __half22float2(hv);
    }
#pragma unroll
    for (int k = 0; k < NB; ++k) {
        float m = (!MASK || (k < rem)) ? 1.0f : 0.0f;
        acc[k & 3].x = fmaf(v[k].x, m, acc[k & 3].x);
        acc[k & 3].y = fmaf(v[k].y, m, acc[k & 3].y);
    }
}

template <int NB, bool MASK>
__device__ __forceinline__ void batch_f64(const int* __restrict__ csr, int j, int rem,
                                          const __half* __restrict__ xwh, int lane,
                                          float* acc) {
    int s[NB];
#pragma unroll
    for (int k = 0; k < NB; ++k) {
        int jj = MASK ? (j + ((k < rem) ? k : 0)) : (j + k);
        s[k] = csr[jj];
    }
    float v[NB];
#pragma unroll
    for (int k = 0; k < NB; ++k)
        v[k] = __half2float(xwh[(size_t)s[k] * 64 + lane]);
#pragma unroll
    for (int k = 0; k < NB; ++k) {
        float m = (!MASK || (k < rem)) ? 1.0f : 0.0f;
        acc[k & 3] = fmaf(v[k], m, acc[k & 3]);
    }
}

// --- fused aggregate: o = dinv[i]*sum_j xwh[src_j] + xw[i]*dinv^2 + b ---
// MODE 0 (F=128): write bf16 hi/lo pair (next gemm's A operand), no relu.
// MODE 1 (F=64): write fp32 + relu (final output).
template <int F, int MODE>
__global__ __launch_bounds__(256) void agg_kernel(const int* __restrict__ rowptr,
                                                  const int* __restrict__ csr,
                                                  const float* __restrict__ xw,
                                                  const __half* __restrict__ xwh,
                                                  const float* __restrict__ dinv,
                                                  const float* __restrict__ bias,
                                                  float* __restrict__ out,
                                                  unsigned short* __restrict__ outHi,
                                                  unsigned short* __restrict__ outLo,
                                                  int n) {
    int wave = threadIdx.x >> 6;
    int lane = threadIdx.x & 63;
    int i0 = blockIdx.x * 4 + wave;
    if (i0 >= n) return;
    int i = __builtin_amdgcn_readfirstlane(i0);
    float di = dinv[i];
    float d2 = di * di;
    int j = rowptr[i];
    int end = rowptr[i + 1];
    j = __builtin_amdgcn_readfirstlane(j);
    end = __builtin_amdgcn_readfirstlane(end);

    if constexpr (F == 128) {
        float2 x0 = ((const float2*)(xw + (size_t)i * F))[lane];
        float2 acc[4];
        acc[0] = acc[1] = acc[2] = acc[3] = make_float2(0.f, 0.f);

        for (; j + 16 <= end; j += 16) batch_f128<16, false>(csr, j, 0, xwh, lane, acc);
        if (j + 8 <= end) { batch_f128<8, false>(csr, j, 0, xwh, lane, acc); j += 8; }
        if (j + 4 <= end) { batch_f128<4, false>(csr, j, 0, xwh, lane, acc); j += 4; }
        int rem = end - j;
        if (rem > 0) batch_f128<4, true>(csr, j, rem, xwh, lane, acc);

        float2 bv = ((const float2*)bias)[lane];
        float ox = fmaf(di, (acc[0].x + acc[1].x) + (acc[2].x + acc[3].x),
                        fmaf(x0.x, d2, bv.x));
        float oy = fmaf(di, (acc[0].y + acc[1].y) + (acc[2].y + acc[3].y),
                        fmaf(x0.y, d2, bv.y));
        unsigned short h0 = bf16_rne(ox);
        unsigned short l0 = bf16_rne(ox - bf16_f(h0));
        unsigned short h1 = bf16_rne(oy);
        unsigned short l1 = bf16_rne(oy - bf16_f(h1));
        ((unsigned*)(outHi + (size_t)i * F))[lane] = (unsigned)h0 | ((unsigned)h1 << 16);
        ((unsigned*)(outLo + (size_t)i * F))[lane] = (unsigned)l0 | ((unsigned)l1 << 16);
    } else {  // F == 64, final layer
        float x0 = xw[(size_t)i * F + lane];
        float acc[4] = {0.f, 0.f, 0.f, 0.f};

        for (; j + 16 <= end; j += 16) batch_f64<16, false>(csr, j, 0, xwh, lane, acc);
        if (j + 8 <= end) { batch_f64<8, false>(csr, j, 0, xwh, lane, acc); j += 8; }
        if (j + 4 <= end) { batch_f64<4, false>(csr, j, 0, xwh, lane, acc); j += 4; }
        int rem = end - j;
        if (rem > 0) batch_f64<4, true>(csr, j, rem, xwh, lane, acc);

        float o = fmaf(di, (acc[0] + acc[1]) + (acc[2] + acc[3]),
                       fmaf(x0, d2, bias[lane]));
        o = fmaxf(o, 0.f);
        out[(size_t)i * F + lane] = o;
    }
}

extern "C" void kernel_launch(void* const* d_in, const int* in_sizes, int n_in,
                              void* d_out, int out_size, void* d_ws, size_t ws_size,
                              hipStream_t stream) {
    const float* x  = (const float*)d_in[0];
    const int*   ei = (const int*)d_in[1];
    const float* W1 = (const float*)d_in[2];
    const float* b1 = (const float*)d_in[3];
    const float* W2 = (const float*)d_in[4];
    const float* b2 = (const float*)d_in[5];
    const float* W3 = (const float*)d_in[6];
    const float* b3 = (const float*)d_in[7];
    float* out = (float*)d_out;

    int E = in_sizes[1] / 2;
    int n = in_sizes[0] / C_IN;
    const int* src = ei;
    const int* dst = ei + E;
    int nbuk = (n + 255) >> 8;

    // workspace layout (16B-aligned segments)
    float*          A    = (float*)d_ws;                        // [n*128] gemm Y fp32
    __half*         Ah   = (__half*)(A + (size_t)n * C_HID);    // [n*128] dinv*Y fp16
    unsigned short* Bhi  = (unsigned short*)(Ah + (size_t)n * C_HID); // [n*128] bf16 hi
    unsigned short* Blo  = Bhi + (size_t)n * C_HID;             // [n*128] bf16 lo
    unsigned short* Wf   = Blo + (size_t)n * C_HID;             // [81920] frag W
    int2*           ebuf = (int2*)(Wf + 81920);                 // [E]
    int*            csr  = (int*)(ebuf + E);                    // [E]
    float*          dinv = (float*)(csr + E);                   // [n]
    int*            rowptr = (int*)(dinv + n);                  // [n+1]
    int*            bukCnt = rowptr + n + 1;                    // [256]
    int*            bbase  = bukCnt + 256;                      // [nbuk+1]
    int*            cursor = bbase + 256 + 1;                   // [256]

    // Wf sub-regions (ushort offsets)
    unsigned short* W1h = Wf;            // 16384
    unsigned short* W1l = Wf + 16384;
    unsigned short* W2h = Wf + 32768;
    unsigned short* W2l = Wf + 49152;
    unsigned short* W3h = Wf + 65536;
    unsigned short* W3l = Wf + 73728;

    // ---- CSR build ----
    hipMemsetAsync(bukCnt, 0, 256 * sizeof(int), stream);
    buk_hist_kernel<<<PART_BLOCKS, 256, 0, stream>>>(dst, E, bukCnt);
    buk_scan_kernel<<<1, 256, 0, stream>>>(bukCnt, nbuk, E, bbase, cursor);
    buk_place_kernel<<<PART_BLOCKS, 256, 0, stream>>>(src, dst, E, cursor, ebuf);
    buk_fill_kernel<<<nbuk, 256, 0, stream>>>(ebuf, bbase, n, E, rowptr, dinv, csr);

    // ---- one-time precompute: W frag split + layer-1 x split ----
    wsplit_all_kernel<<<20, 256, 0, stream>>>(W1, W2, W3, Wf);
    int total4 = n * C_IN / 4;
    split_kernel<<<(total4 + 255) / 256, 256, 0, stream>>>(x, Bhi, Blo, total4);

    int aggBlocks = (n + 3) / 4;
    int rowTiles = (n + 63) / 64;   // 782

    // ---- layer 1 ----
    gemm_mfma<C_HID><<<rowTiles * 2, 256, 0, stream>>>(Bhi, Blo, W1h, W1l, dinv, A, Ah, n);
    agg_kernel<C_HID, 0><<<aggBlocks, 256, 0, stream>>>(rowptr, csr, A, Ah, dinv, b1,
                                                        nullptr, Bhi, Blo, n);
    // ---- layer 2 ----
    gemm_mfma<C_HID><<<rowTiles * 2, 256, 0, stream>>>(Bhi, Blo, W2h, W2l, dinv, A, Ah, n);
    agg_kernel<C_HID, 0><<<aggBlocks, 256, 0, stream>>>(rowptr, csr, A, Ah, dinv, b2,
                                                        nullptr, Bhi, Blo, n);
    // ---- layer 3 ----
    gemm_mfma<C_OUT><<<rowTiles, 256, 0, stream>>>(Bhi, Blo, W3h, W3l, dinv, A, Ah, n);
    agg_kernel<C_OUT, 1><<<aggBlocks, 256, 0, stream>>>(rowptr, csr, A, Ah, dinv, b3,
                                                        out, nullptr, nullptr, n);
}